// Round 7
// baseline (321.951 us; speedup 1.0000x reference)
//
#include <hip/hip_runtime.h>
#include <math.h>

// Problem constants
constexpr int B    = 256;
constexpr int S    = 512;
constexpr int E    = 256;
constexpr int PD   = 32;
constexpr int FN   = 230;
constexpr int FNP  = 256;
constexpr int TAG  = 53;
constexpr int BM   = 128;   // s-rows per block
constexpr int NG   = 10;    // feature groups (320/32)

typedef short  bf16x8 __attribute__((ext_vector_type(8)));
typedef float  f32x4  __attribute__((ext_vector_type(4)));

__device__ __forceinline__ unsigned f2bf(float x) {
    union { float f; unsigned u; } v; v.f = x;
    unsigned r = v.u + 0x7FFF + ((v.u >> 16) & 1);   // RNE
    return r >> 16;
}
__device__ __forceinline__ unsigned pack2(float a, float b) {
    return f2bf(a) | (f2bf(b) << 16);
}

// async global->LDS, 16 B per lane; LDS dest = wave-uniform base + lane*16
__device__ __forceinline__ void gl_lds16(const void* g, void* l) {
    __builtin_amdgcn_global_load_lds(
        (const __attribute__((address_space(1))) unsigned int*)g,
        (__attribute__((address_space(3))) unsigned int*)l, 16, 0, 0);
}

// ---------------------------------------------------------------------------
// Prep kernel: blocks [0,240): build wt2 (permuted bf16 weights);
//              blocks [240,496): per-batch bounds + zero pcnn.
// wt2 layout: [n][g][w][q][e] : n*960 + g*96 + w*32 + q*8 + e  (bf16)
//   holds conv_w[k][n] with k = w*320 + g*32 + q*8 + e, zero-pad n>=230.
// ---------------------------------------------------------------------------
__global__ __launch_bounds__(256) void prep_kernel(
    const float* __restrict__ conv_w, const int* __restrict__ pos1,
    const int* __restrict__ pos2, unsigned short* __restrict__ wt2,
    int* __restrict__ segb, unsigned* __restrict__ pcnn)
{
    const int bid = blockIdx.x;
    const int tid = threadIdx.x;
    if (bid < 240) {
        __shared__ float tile[32][33];
        const int kb = bid % 30, nb = bid / 30;
        const int k0 = kb * 32, n0 = nb * 32;
        const int tx = tid & 31, ty = tid >> 5;
#pragma unroll
        for (int i = 0; i < 4; ++i) {
            int k = k0 + ty + i * 8, n = n0 + tx;
            tile[ty + i * 8][tx] = (n < FN) ? conv_w[(size_t)k * FN + n] : 0.0f;
        }
        __syncthreads();
        const int g = (k0 >> 5) % 10, w = k0 / 320;   // k0 = w*320 + g*32
#pragma unroll
        for (int i = 0; i < 4; ++i) {
            int n = n0 + ty + i * 8;
            wt2[(size_t)n * 960 + g * 96 + w * 32 + tx] =
                (unsigned short)f2bf(tile[tx][ty + i * 8]);
        }
    } else {
        const int b = bid - 240;
        __shared__ int r[4];
        if (tid == 0) { r[0] = S; r[1] = -1; r[2] = S; r[3] = -1; }
        __syncthreads();
        for (int s = tid; s < S; s += 256) {
            if (pos1[b * S + s] == 60) { atomicMin(&r[0], s); atomicMax(&r[1], s); }
            if (pos2[b * S + s] == 60) { atomicMin(&r[2], s); atomicMax(&r[3], s); }
        }
        __syncthreads();
        if (tid == 0) {
            int p1min = r[0], p1max = r[1], p2min = r[2], p2max = r[3];
            bool first = p1min < p2min;
            int m1 = first ? p1min : p2min;
            int m2 = first ? p1max : p2max;
            int m3 = first ? p2min : p1min;
            int m4 = first ? p2max : p1max;
            int4 o;
            o.x = max(m1, 1);
            o.y = m2;
            o.z = max(m3, m2 + 1);
            o.w = m4;
            *(int4*)(segb + b * 4) = o;
        }
        unsigned* pc = pcnn + (size_t)b * 3 * FNP;
        for (int i = tid; i < 3 * FNP; i += 256) pc[i] = 0u;
    }
}

// ---------------------------------------------------------------------------
// Conv kernel: fused gather + conv1d(win3,pad1) bf16 MFMA + bias+ReLU+segmax
// grid (S/BM=4, B); 512 thr = 8 waves (2M x 4N), wave tile 64x64.
// Per group g (32 feats): ONE 48KB B-stage (all 3 windows, global_load_lds,
// chunk-major LDS [j12][n256]), A gather reg-prefetched one group ahead,
// single vmcnt(0) drain per group, raw s_barriers.
// ---------------------------------------------------------------------------
__global__ __launch_bounds__(512, 4) void conv_mfma_kernel(
    const int* __restrict__ sentence, const int* __restrict__ pos1,
    const int* __restrict__ pos2,
    const float* __restrict__ word_emb, const float* __restrict__ pos1_emb,
    const float* __restrict__ pos2_emb,
    const unsigned short* __restrict__ wt2, const float* __restrict__ conv_b,
    const int* __restrict__ segb, unsigned* __restrict__ pcnn)
{
    __shared__ __align__(16) unsigned short ldsB[12 * 256 * 8]; // 49152 B
    __shared__ __align__(16) unsigned short ldsA[528 * 8];      //  8448 B
    __shared__ unsigned maxbuf[3 * FNP];                        //  3072 B

    const int tid  = threadIdx.x;
    const int b    = blockIdx.y;
    const int s0   = blockIdx.x * BM;
    const int lane = tid & 63;
    const int wid  = tid >> 6;
    const int wm   = wid >> 2;
    const int wn   = wid & 3;
    const int lrow = lane & 15;
    const int lgrp = lane >> 4;

    for (int i = tid; i < 3 * FNP; i += 512) maxbuf[i] = 0u;

    // ---- A-chunk assignment: chunk j -> (q = j/132, r = j%132), row s = s0-1+r
    const int q0 = (tid >= 396) ? 3 : (tid >= 264) ? 2 : (tid >= 132) ? 1 : 0;
    const int r0 = tid - q0 * 132;
    const int sA0 = s0 - 1 + r0;
    const bool v0 = (unsigned)sA0 < (unsigned)S;
    const int sid0 = v0 ? sentence[b * S + sA0] : 0;
    const int p10  = v0 ? pos1[b * S + sA0] : 0;
    const int p20  = v0 ? pos2[b * S + sA0] : 0;
    // extra chunks 512..527 handled by tid<16: (q=3, r=116+tid)
    const int r1   = 116 + tid;
    const int sA1  = s0 - 1 + r1;
    const bool v1  = (tid < 16) && ((unsigned)sA1 < (unsigned)S);
    const int sid1 = v1 ? sentence[b * S + sA1] : 0;
    const int p11  = v1 ? pos1[b * S + sA1] : 0;
    const int p21  = v1 ? pos2[b * S + sA1] : 0;

    // ---- B-stage source offsets: chunk j = rep*512 + tid; n=j&255, c=2*rep+(tid>>8)
    const size_t bnoff = (size_t)(tid & 255) * 1920;   // bytes (960 bf16 per n-row)
    const int    bc0   = tid >> 8;                     // 0 or 1
    const char*  wt2c  = (const char*)wt2;

    f32x4 acc[4][4];
#pragma unroll
    for (int i = 0; i < 4; ++i)
#pragma unroll
        for (int j = 0; j < 4; ++j) acc[i][j] = (f32x4){0.f, 0.f, 0.f, 0.f};

    // A source selector (g uniform)
    auto srcA = [&](int g, int sid, int p1v, int p2v, int qq) -> const float* {
        if (g < 8)  return word_emb + (size_t)sid * E + g * 32 + qq * 8;
        if (g == 8) return pos1_emb + p1v * PD + qq * 8;
        return pos2_emb + p2v * PD + qq * 8;
    };

    // prologue: prefetch A(0) into regs
    float4 am0, am1, ae0, ae1;
    {
        const float* p = srcA(0, sid0, p10, p20, q0);
        am0 = *(const float4*)p; am1 = *(const float4*)(p + 4);
        if (tid < 16) {
            const float* pe = srcA(0, sid1, p11, p21, 3);
            ae0 = *(const float4*)pe; ae1 = *(const float4*)(pe + 4);
        }
    }

    for (int g = 0; g < NG; ++g) {
        __builtin_amdgcn_s_barrier();          // buffers free (prev reads consumed)
        // ---- stage B(g): 6 x global_load_lds per thread (48 KB total) ----
#pragma unroll
        for (int rep = 0; rep < 6; ++rep) {
            const void* src = wt2c + bnoff + (size_t)(g * 12 + 2 * rep + bc0) * 16;
            void* dst = (char*)ldsB + (rep * 512 + wid * 64) * 16;
            gl_lds16(src, dst);
        }
        // ---- pack + ds_write A(g) (compiler waits the older A loads only) ----
        {
            uint4 pk;
            pk.x = pack2(am0.x, am0.y); pk.y = pack2(am0.z, am0.w);
            pk.z = pack2(am1.x, am1.y); pk.w = pack2(am1.z, am1.w);
            if (!v0) pk = make_uint4(0u, 0u, 0u, 0u);
            *(uint4*)&ldsA[(q0 * 132 + r0) * 8] = pk;
            if (tid < 16) {
                uint4 pe;
                pe.x = pack2(ae0.x, ae0.y); pe.y = pack2(ae0.z, ae0.w);
                pe.z = pack2(ae1.x, ae1.y); pe.w = pack2(ae1.z, ae1.w);
                if (!v1) pe = make_uint4(0u, 0u, 0u, 0u);
                *(uint4*)&ldsA[(3 * 132 + r1) * 8] = pe;
            }
        }
        asm volatile("s_waitcnt vmcnt(0) lgkmcnt(0)" ::: "memory");
        __builtin_amdgcn_sched_barrier(0);
        // ---- prefetch A(g+1) (in flight across barrier + compute) ----
        if (g < NG - 1) {
            const float* p = srcA(g + 1, sid0, p10, p20, q0);
            am0 = *(const float4*)p; am1 = *(const float4*)(p + 4);
            if (tid < 16) {
                const float* pe = srcA(g + 1, sid1, p11, p21, 3);
                ae0 = *(const float4*)pe; ae1 = *(const float4*)(pe + 4);
            }
        }
        __builtin_amdgcn_s_barrier();          // stage(g) visible to all
        __builtin_amdgcn_sched_barrier(0);
        // ---- compute group g: 3 windows x 16 MFMA ----
#pragma unroll
        for (int w = 0; w < 3; ++w) {
            bf16x8 af[4], bfr[4];
#pragma unroll
            for (int mi = 0; mi < 4; ++mi)
                af[mi] = *(const bf16x8*)&ldsA[(lgrp * 132 + wm * 64 + mi * 16 + lrow + w) * 8];
#pragma unroll
            for (int ni = 0; ni < 4; ++ni)
                if (wn * 64 + ni * 16 < FN)
                    bfr[ni] = *(const bf16x8*)&ldsB[((w * 4 + lgrp) * 256 + wn * 64 + ni * 16 + lrow) * 8];
            __builtin_amdgcn_s_setprio(1);
#pragma unroll
            for (int mi = 0; mi < 4; ++mi)
#pragma unroll
                for (int ni = 0; ni < 4; ++ni)
                    if (wn * 64 + ni * 16 < FN)
                        acc[mi][ni] = __builtin_amdgcn_mfma_f32_16x16x32_bf16(
                            af[mi], bfr[ni], acc[mi][ni], 0, 0, 0);
            __builtin_amdgcn_s_setprio(0);
        }
    }

    // ---- epilogue: bias + ReLU + segment max ----
    const int4 sb = *(const int4*)(segb + b * 4);
    float biasv[4];
#pragma unroll
    for (int ni = 0; ni < 4; ++ni) {
        int f = wn * 64 + ni * 16 + lrow;
        biasv[ni] = (f < FN) ? conv_b[f] : 0.0f;
    }
#pragma unroll
    for (int mi = 0; mi < 4; ++mi) {
#pragma unroll
        for (int rr = 0; rr < 4; ++rr) {
            int s = s0 + wm * 64 + mi * 16 + lgrp * 4 + rr;
            int mask = 0;
            if (s < sb.x) mask |= 1;
            if (s >= sb.y && s < sb.z) mask |= 2;
            if (s >= sb.w) mask |= 4;
            if (!mask) continue;
#pragma unroll
            for (int ni = 0; ni < 4; ++ni) {
                int f = wn * 64 + ni * 16 + lrow;
                if (f >= FN) continue;
                float v = fmaxf(acc[mi][ni][rr] + biasv[ni], 0.0f);
                unsigned uv = __float_as_uint(v);
                if (mask & 1) atomicMax(&maxbuf[f], uv);
                if (mask & 2) atomicMax(&maxbuf[FNP + f], uv);
                if (mask & 4) atomicMax(&maxbuf[2 * FNP + f], uv);
            }
        }
    }
    __syncthreads();
    unsigned* pc = pcnn + (size_t)b * 3 * FNP;
    for (int i = tid; i < 3 * FNP; i += 512) {
        unsigned m = maxbuf[i];
        if (((i & (FNP - 1)) < FN) && m) atomicMax(pc + i, m);
    }
}

// ---------------------------------------------------------------------------
// Finale: tanh, 3-way softmax attention, rel_emb GEMV, tag softmax
// ---------------------------------------------------------------------------
__global__ __launch_bounds__(256) void finale_kernel(
    const float* __restrict__ pcnn, const float* __restrict__ att_weight,
    const float* __restrict__ rel_emb, const float* __restrict__ rel_bias,
    float* __restrict__ out)
{
    const int b = blockIdx.x;
    const int tid = threadIdx.x;
    __shared__ float red[12];
    __shared__ float satt[FN];
    __shared__ float wtag[56];

    const float* pc = pcnn + (size_t)b * 3 * FNP;
    float p0 = 0.f, p1 = 0.f, p2 = 0.f, aw = 0.f;
    if (tid < FN) {
        p0 = pc[tid];
        p1 = pc[FNP + tid];
        p2 = pc[2 * FNP + tid];
        aw = att_weight[b * FN + tid];
    }
    const int wid = tid >> 6;
#pragma unroll
    for (int t = 0; t < 3; ++t) {
        float pt = (t == 0) ? p0 : (t == 1) ? p1 : p2;
        float r = (tid < FN) ? aw * tanhf(pt) : 0.0f;
#pragma unroll
        for (int o = 32; o; o >>= 1) r += __shfl_xor(r, o);
        if ((tid & 63) == 0) red[t * 4 + wid] = r;
    }
    __syncthreads();
    float sc0 = red[0] + red[1] + red[2] + red[3];
    float sc1 = red[4] + red[5] + red[6] + red[7];
    float sc2 = red[8] + red[9] + red[10] + red[11];
    float m3s = fmaxf(sc0, fmaxf(sc1, sc2));
    float e0 = expf(sc0 - m3s), e1 = expf(sc1 - m3s), e2 = expf(sc2 - m3s);
    float inv = 1.0f / (e0 + e1 + e2);
    float a0 = e0 * inv, a1 = e1 * inv, a2 = e2 * inv;
    if (tid < FN) satt[tid] = tanhf(p0 * a0 + p1 * a1 + p2 * a2);
    __syncthreads();

    const int t = tid >> 2;
    const int part = tid & 3;
    if (t < TAG) {
        float s = 0.0f;
        for (int f = part; f < FN; f += 4) s += rel_emb[t * FN + f] * satt[f];
        s += __shfl_xor(s, 1);
        s += __shfl_xor(s, 2);
        if (part == 0) wtag[t] = s + rel_bias[b * TAG + t];
    }
    __syncthreads();

    if (tid < 64) {
        float v = (tid < TAG) ? wtag[tid] : -1e30f;
        float mx = v;
#pragma unroll
        for (int o = 32; o; o >>= 1) mx = fmaxf(mx, __shfl_xor(mx, o));
        float e = (tid < TAG) ? expf(v - mx) : 0.0f;
        float sum = e;
#pragma unroll
        for (int o = 32; o; o >>= 1) sum += __shfl_xor(sum, o);
        if (tid < TAG) out[b * TAG + tid] = e / sum;
    }
}

// ---------------------------------------------------------------------------
extern "C" void kernel_launch(void* const* d_in, const int* in_sizes, int n_in,
                              void* d_out, int out_size, void* d_ws, size_t ws_size,
                              hipStream_t stream)
{
    const int*   sentence  = (const int*)d_in[0];
    const int*   pos1      = (const int*)d_in[1];
    const int*   pos2      = (const int*)d_in[2];
    const float* word_emb  = (const float*)d_in[3];
    const float* pos1_emb  = (const float*)d_in[4];
    const float* pos2_emb  = (const float*)d_in[5];
    const float* rel_emb   = (const float*)d_in[6];
    const float* conv_w    = (const float*)d_in[7];
    const float* conv_b    = (const float*)d_in[8];
    const float* att_w     = (const float*)d_in[9];
    const float* rel_bias  = (const float*)d_in[10];
    float* out = (float*)d_out;

    // workspace layout
    int*            segb = (int*)d_ws;                                     //   4096 B
    unsigned*       pcnn = (unsigned*)((char*)d_ws + 4096);                // 786432 B
    unsigned short* wt2  = (unsigned short*)((char*)d_ws + 4096 + 786432); // 491520 B

    prep_kernel<<<240 + B, 256, 0, stream>>>(conv_w, pos1, pos2, wt2, segb, pcnn);
    conv_mfma_kernel<<<dim3(S / BM, B), 512, 0, stream>>>(
        sentence, pos1, pos2, word_emb, pos1_emb, pos2_emb,
        wt2, conv_b, segb, pcnn);
    finale_kernel<<<B, 256, 0, stream>>>(
        (const float*)pcnn, att_w, rel_emb, rel_bias, out);
}

// Round 8
// 189.200 us; speedup vs baseline: 1.7016x; 1.7016x over previous
//
#include <hip/hip_runtime.h>
#include <math.h>

// Problem constants
constexpr int B    = 256;
constexpr int S    = 512;
constexpr int E    = 256;
constexpr int PD   = 32;
constexpr int FN   = 230;
constexpr int FNP  = 256;
constexpr int TAG  = 53;
constexpr int BM   = 128;   // s-rows per block
constexpr int NG   = 10;    // feature groups (320/32)

typedef short  bf16x8 __attribute__((ext_vector_type(8)));
typedef float  f32x4  __attribute__((ext_vector_type(4)));

__device__ __forceinline__ unsigned f2bf(float x) {
    union { float f; unsigned u; } v; v.f = x;
    unsigned r = v.u + 0x7FFF + ((v.u >> 16) & 1);   // RNE
    return r >> 16;
}
__device__ __forceinline__ unsigned pack2(float a, float b) {
    return f2bf(a) | (f2bf(b) << 16);
}

// async global->LDS, 16 B per lane; LDS dest = wave-uniform base + lane*16,
// global src address is PER-LANE.
__device__ __forceinline__ void gl_lds16(const void* g, void* l) {
    __builtin_amdgcn_global_load_lds(
        (const __attribute__((address_space(1))) unsigned int*)g,
        (__attribute__((address_space(3))) unsigned int*)l, 16, 0, 0);
}

// workspace offsets (bytes)
constexpr size_t WS_SEGB  = 0;           //   4096
constexpr size_t WS_PCNN  = 4096;        // 786432
constexpr size_t WS_WT3   = 790528;      // 491520
constexpr size_t WS_ZERO  = 1282048;     //    256
constexpr size_t WS_WEMB  = 1282304;     // 25600000 (50000*256 bf16)
constexpr size_t WS_P1H   = 26882304;    //   7744  (121*32 bf16)
constexpr size_t WS_P2H   = 26890048;    //   7744

// ---------------------------------------------------------------------------
// Prep kernel, grid = 6750 blocks x 256:
//  [0,6250)      : word_emb f32 -> bf16 (2048 elems/block)
//  [6250,6252)   : pos1_emb -> bf16
//  [6252,6254)   : pos2_emb -> bf16
//  [6254,6494)   : wt3 build (240 blocks), staging-ordered bf16 weights:
//     wt3[g*24576 + ((w*4+q)*256 + n)*8 + e] = conv_w[w*320+g*32+q*8+e][n]
//  [6494,6750)   : per-batch bounds + zero pcnn (+ zerobuf in first block)
// ---------------------------------------------------------------------------
__global__ __launch_bounds__(256) void prep_kernel(
    const float* __restrict__ conv_w, const int* __restrict__ pos1,
    const int* __restrict__ pos2,
    const float* __restrict__ word_emb, const float* __restrict__ pos1_emb,
    const float* __restrict__ pos2_emb, char* __restrict__ ws)
{
    const int bid = blockIdx.x;
    const int tid = threadIdx.x;
    if (bid < 6250) {
        // word_emb conversion: 12.8M elems exactly = 6250 * 2048
        unsigned short* wembh = (unsigned short*)(ws + WS_WEMB);
        const size_t base = (size_t)bid * 2048 + tid * 8;
        float4 a = *(const float4*)(word_emb + base);
        float4 b = *(const float4*)(word_emb + base + 4);
        uint4 pk;
        pk.x = pack2(a.x, a.y); pk.y = pack2(a.z, a.w);
        pk.z = pack2(b.x, b.y); pk.w = pack2(b.z, b.w);
        *(uint4*)((unsigned short*)wembh + base) = pk;
    } else if (bid < 6254) {
        const bool isP2 = bid >= 6252;
        const int  blk  = bid - (isP2 ? 6252 : 6250);
        const float* src = isP2 ? pos2_emb : pos1_emb;
        unsigned short* dst = (unsigned short*)(ws + (isP2 ? WS_P2H : WS_P1H));
        int base = blk * 2048 + tid * 8;
        if (base + 7 < 121 * 32) {
            float4 a = *(const float4*)(src + base);
            float4 b = *(const float4*)(src + base + 4);
            uint4 pk;
            pk.x = pack2(a.x, a.y); pk.y = pack2(a.z, a.w);
            pk.z = pack2(b.x, b.y); pk.w = pack2(b.z, b.w);
            *(uint4*)(dst + base) = pk;
        }
    } else if (bid < 6494) {
        unsigned short* wt3 = (unsigned short*)(ws + WS_WT3);
        __shared__ float tile[32][33];
        const int tbid = bid - 6254;
        const int kb = tbid % 30, nb = tbid / 30;
        const int k0 = kb * 32, n0 = nb * 32;
        const int tx = tid & 31, ty = tid >> 5;
#pragma unroll
        for (int i = 0; i < 4; ++i) {
            int k = k0 + ty + i * 8, n = n0 + tx;
            tile[ty + i * 8][tx] = (n < FN) ? conv_w[(size_t)k * FN + n] : 0.0f;
        }
        __syncthreads();
        const int g = (k0 % 320) >> 5, w = k0 / 320;
        const int q = tx >> 3, e = tx & 7;
#pragma unroll
        for (int i = 0; i < 4; ++i) {
            int n = n0 + ty + i * 8;
            wt3[g * 24576 + ((w * 4 + q) * 256 + n) * 8 + e] =
                (unsigned short)f2bf(tile[tx][ty + i * 8]);
        }
    } else {
        const int b = bid - 6494;
        int* segb = (int*)(ws + WS_SEGB);
        unsigned* pcnn = (unsigned*)(ws + WS_PCNN);
        if (b == 0 && tid < 64) ((unsigned*)(ws + WS_ZERO))[tid] = 0u;
        __shared__ int r[4];
        if (tid == 0) { r[0] = S; r[1] = -1; r[2] = S; r[3] = -1; }
        __syncthreads();
        for (int s = tid; s < S; s += 256) {
            if (pos1[b * S + s] == 60) { atomicMin(&r[0], s); atomicMax(&r[1], s); }
            if (pos2[b * S + s] == 60) { atomicMin(&r[2], s); atomicMax(&r[3], s); }
        }
        __syncthreads();
        if (tid == 0) {
            int p1min = r[0], p1max = r[1], p2min = r[2], p2max = r[3];
            bool first = p1min < p2min;
            int m1 = first ? p1min : p2min;
            int m2 = first ? p1max : p2max;
            int m3 = first ? p2min : p1min;
            int m4 = first ? p2max : p1max;
            int4 o;
            o.x = max(m1, 1);
            o.y = m2;
            o.z = max(m3, m2 + 1);
            o.w = m4;
            *(int4*)(segb + b * 4) = o;
        }
        unsigned* pc = pcnn + (size_t)b * 3 * FNP;
        for (int i = tid; i < 3 * FNP; i += 256) pc[i] = 0u;
    }
}

// ---------------------------------------------------------------------------
// Conv kernel: fused gather + conv1d(win3,pad1) bf16 MFMA + bias+ReLU+segmax
// grid (4, 256); 512 thr = 8 waves (2M x 4N), wave tile 64x64.
// All staging via global_load_lds (A: per-lane bf16-emb gather; B: contiguous
// wt3 block). One vmcnt(0) drain + 2 raw s_barriers per group. No spills:
// no persistent prefetch regs, acc in AGPRs, ~120 regs < 128 budget.
// ---------------------------------------------------------------------------
__global__ __launch_bounds__(512, 4) void conv_mfma_kernel(
    const int* __restrict__ sentence, const int* __restrict__ pos1,
    const int* __restrict__ pos2, const float* __restrict__ conv_b,
    const char* __restrict__ ws_ro, char* __restrict__ ws)
{
    __shared__ __align__(16) unsigned short ldsB[12 * 256 * 8]; // 49152 B
    __shared__ __align__(16) unsigned short ldsA[520 * 8];      //  8320 B
    __shared__ unsigned maxbuf[3 * FNP];                        //  3072 B

    const unsigned short* wembh = (const unsigned short*)(ws_ro + WS_WEMB);
    const unsigned short* p1h   = (const unsigned short*)(ws_ro + WS_P1H);
    const unsigned short* p2h   = (const unsigned short*)(ws_ro + WS_P2H);
    const unsigned short* zb    = (const unsigned short*)(ws_ro + WS_ZERO);
    const char* wt3c            = ws_ro + WS_WT3;
    const int* segb             = (const int*)(ws_ro + WS_SEGB);
    unsigned* pcnn              = (unsigned*)(ws + WS_PCNN);

    const int tid  = threadIdx.x;
    const int b    = blockIdx.y;
    const int s0   = blockIdx.x * BM;
    const int lane = tid & 63;
    const int wid  = tid >> 6;
    const int wm   = wid >> 2;
    const int wn   = wid & 3;
    const int lrow = lane & 15;
    const int lgrp = lane >> 4;

    for (int i = tid; i < 3 * FNP; i += 512) maxbuf[i] = 0u;

    // ---- A-unit assignment: unit u = q*130 + r, row r -> s = s0-1+r ----
    const int q0 = (tid >= 390) ? 3 : (tid >= 260) ? 2 : (tid >= 130) ? 1 : 0;
    const int r0 = tid - q0 * 130;
    const int sA0 = s0 - 1 + r0;
    const bool v0 = (unsigned)sA0 < (unsigned)S;
    const int sid0 = v0 ? sentence[b * S + sA0] : 0;
    const int p10  = v0 ? pos1[b * S + sA0] : 0;
    const int p20  = v0 ? pos2[b * S + sA0] : 0;
    // tail units 512..519: tid<8, q=3, r=122+tid
    const int r1   = 122 + tid;
    const int sA1  = s0 - 1 + r1;
    const bool v1  = (tid < 8) && ((unsigned)sA1 < (unsigned)S);
    const int sid1 = v1 ? sentence[b * S + sA1] : 0;
    const int p11  = v1 ? pos1[b * S + sA1] : 0;
    const int p21  = v1 ? pos2[b * S + sA1] : 0;

    auto srch = [&](int g, int sid, int p1v, int p2v, int qq) -> const unsigned short* {
        if (g < 8)  return wembh + (size_t)sid * E + g * 32 + qq * 8;
        if (g == 8) return p1h + p1v * PD + qq * 8;
        return p2h + p2v * PD + qq * 8;
    };

    f32x4 acc[4][4];
#pragma unroll
    for (int i = 0; i < 4; ++i)
#pragma unroll
        for (int j = 0; j < 4; ++j) acc[i][j] = (f32x4){0.f, 0.f, 0.f, 0.f};

    for (int g = 0; g < NG; ++g) {
        __builtin_amdgcn_s_barrier();   // previous tiles fully consumed
        // ---- stage B(g): 6 gl_lds, contiguous 48KB block of wt3 ----
#pragma unroll
        for (int rep = 0; rep < 6; ++rep) {
            const void* src = wt3c + (size_t)g * 49152 + (size_t)(rep * 512 + tid) * 16;
            void* dst = (char*)ldsB + (rep * 512 + wid * 64) * 16;
            gl_lds16(src, dst);
        }
        // ---- stage A(g): per-lane gather from bf16 embeddings ----
        {
            const unsigned short* a0 = v0 ? srch(g, sid0, p10, p20, q0) : zb;
            gl_lds16(a0, (char*)ldsA + (wid * 64) * 16);
            if (tid < 8) {
                const unsigned short* a1 = v1 ? srch(g, sid1, p11, p21, 3) : zb;
                gl_lds16(a1, (char*)ldsA + 512 * 16);
            }
        }
        asm volatile("s_waitcnt vmcnt(0)" ::: "memory");
        __builtin_amdgcn_sched_barrier(0);
        __builtin_amdgcn_s_barrier();   // stage(g) visible to all
        __builtin_amdgcn_sched_barrier(0);
        // ---- compute group g: 3 windows x 16 MFMA ----
#pragma unroll
        for (int w = 0; w < 3; ++w) {
            bf16x8 af[4], bfr[4];
#pragma unroll
            for (int mi = 0; mi < 4; ++mi)
                af[mi] = *(const bf16x8*)&ldsA[(lgrp * 130 + wm * 64 + mi * 16 + lrow + w) * 8];
#pragma unroll
            for (int ni = 0; ni < 4; ++ni)
                if (wn * 64 + ni * 16 < FN)
                    bfr[ni] = *(const bf16x8*)&ldsB[((w * 4 + lgrp) * 256 + wn * 64 + ni * 16 + lrow) * 8];
            __builtin_amdgcn_s_setprio(1);
#pragma unroll
            for (int mi = 0; mi < 4; ++mi)
#pragma unroll
                for (int ni = 0; ni < 4; ++ni)
                    if (wn * 64 + ni * 16 < FN)
                        acc[mi][ni] = __builtin_amdgcn_mfma_f32_16x16x32_bf16(
                            af[mi], bfr[ni], acc[mi][ni], 0, 0, 0);
            __builtin_amdgcn_s_setprio(0);
        }
    }

    // ---- epilogue: bias + ReLU + segment max ----
    const int4 sb = *(const int4*)(segb + b * 4);
    float biasv[4];
#pragma unroll
    for (int ni = 0; ni < 4; ++ni) {
        int f = wn * 64 + ni * 16 + lrow;
        biasv[ni] = (f < FN) ? conv_b[f] : 0.0f;
    }
#pragma unroll
    for (int mi = 0; mi < 4; ++mi) {
#pragma unroll
        for (int rr = 0; rr < 4; ++rr) {
            int s = s0 + wm * 64 + mi * 16 + lgrp * 4 + rr;
            int mask = 0;
            if (s < sb.x) mask |= 1;
            if (s >= sb.y && s < sb.z) mask |= 2;
            if (s >= sb.w) mask |= 4;
            if (!mask) continue;
#pragma unroll
            for (int ni = 0; ni < 4; ++ni) {
                int f = wn * 64 + ni * 16 + lrow;
                if (f >= FN) continue;
                float v = fmaxf(acc[mi][ni][rr] + biasv[ni], 0.0f);
                unsigned uv = __float_as_uint(v);
                if (mask & 1) atomicMax(&maxbuf[f], uv);
                if (mask & 2) atomicMax(&maxbuf[FNP + f], uv);
                if (mask & 4) atomicMax(&maxbuf[2 * FNP + f], uv);
            }
        }
    }
    __syncthreads();
    unsigned* pc = pcnn + (size_t)b * 3 * FNP;
    for (int i = tid; i < 3 * FNP; i += 512) {
        unsigned m = maxbuf[i];
        if (((i & (FNP - 1)) < FN) && m) atomicMax(pc + i, m);
    }
}

// ---------------------------------------------------------------------------
// Finale: tanh, 3-way softmax attention, rel_emb GEMV, tag softmax
// ---------------------------------------------------------------------------
__global__ __launch_bounds__(256) void finale_kernel(
    const float* __restrict__ pcnn, const float* __restrict__ att_weight,
    const float* __restrict__ rel_emb, const float* __restrict__ rel_bias,
    float* __restrict__ out)
{
    const int b = blockIdx.x;
    const int tid = threadIdx.x;
    __shared__ float red[12];
    __shared__ float satt[FN];
    __shared__ float wtag[56];

    const float* pc = pcnn + (size_t)b * 3 * FNP;
    float p0 = 0.f, p1 = 0.f, p2 = 0.f, aw = 0.f;
    if (tid < FN) {
        p0 = pc[tid];
        p1 = pc[FNP + tid];
        p2 = pc[2 * FNP + tid];
        aw = att_weight[b * FN + tid];
    }
    const int wid = tid >> 6;
#pragma unroll
    for (int t = 0; t < 3; ++t) {
        float pt = (t == 0) ? p0 : (t == 1) ? p1 : p2;
        float r = (tid < FN) ? aw * tanhf(pt) : 0.0f;
#pragma unroll
        for (int o = 32; o; o >>= 1) r += __shfl_xor(r, o);
        if ((tid & 63) == 0) red[t * 4 + wid] = r;
    }
    __syncthreads();
    float sc0 = red[0] + red[1] + red[2] + red[3];
    float sc1 = red[4] + red[5] + red[6] + red[7];
    float sc2 = red[8] + red[9] + red[10] + red[11];
    float m3s = fmaxf(sc0, fmaxf(sc1, sc2));
    float e0 = expf(sc0 - m3s), e1 = expf(sc1 - m3s), e2 = expf(sc2 - m3s);
    float inv = 1.0f / (e0 + e1 + e2);
    float a0 = e0 * inv, a1 = e1 * inv, a2 = e2 * inv;
    if (tid < FN) satt[tid] = tanhf(p0 * a0 + p1 * a1 + p2 * a2);
    __syncthreads();

    const int t = tid >> 2;
    const int part = tid & 3;
    if (t < TAG) {
        float s = 0.0f;
        for (int f = part; f < FN; f += 4) s += rel_emb[t * FN + f] * satt[f];
        s += __shfl_xor(s, 1);
        s += __shfl_xor(s, 2);
        if (part == 0) wtag[t] = s + rel_bias[b * TAG + t];
    }
    __syncthreads();

    if (tid < 64) {
        float v = (tid < TAG) ? wtag[tid] : -1e30f;
        float mx = v;
#pragma unroll
        for (int o = 32; o; o >>= 1) mx = fmaxf(mx, __shfl_xor(mx, o));
        float e = (tid < TAG) ? expf(v - mx) : 0.0f;
        float sum = e;
#pragma unroll
        for (int o = 32; o; o >>= 1) sum += __shfl_xor(sum, o);
        if (tid < TAG) out[b * TAG + tid] = e / sum;
    }
}

// ---------------------------------------------------------------------------
extern "C" void kernel_launch(void* const* d_in, const int* in_sizes, int n_in,
                              void* d_out, int out_size, void* d_ws, size_t ws_size,
                              hipStream_t stream)
{
    const int*   sentence  = (const int*)d_in[0];
    const int*   pos1      = (const int*)d_in[1];
    const int*   pos2      = (const int*)d_in[2];
    const float* word_emb  = (const float*)d_in[3];
    const float* pos1_emb  = (const float*)d_in[4];
    const float* pos2_emb  = (const float*)d_in[5];
    const float* rel_emb   = (const float*)d_in[6];
    const float* conv_w    = (const float*)d_in[7];
    // d_in[8] = conv_b, d_in[9] = att_w, d_in[10] = rel_bias
    const float* conv_b    = (const float*)d_in[8];
    const float* att_w     = (const float*)d_in[9];
    const float* rel_bias  = (const float*)d_in[10];
    float* out = (float*)d_out;
    char* ws = (char*)d_ws;

    prep_kernel<<<6750, 256, 0, stream>>>(
        conv_w, pos1, pos2, word_emb, pos1_emb, pos2_emb, ws);
    conv_mfma_kernel<<<dim3(S / BM, B), 512, 0, stream>>>(
        sentence, pos1, pos2, conv_b, ws, ws);
    finale_kernel<<<B, 256, 0, stream>>>(
        (const float*)(ws + WS_PCNN), att_w, rel_emb, rel_bias, out);
}